// Round 2
// baseline (7426.028 us; speedup 1.0000x reference)
//
#include <hip/hip_runtime.h>
#include <hip/hip_bf16.h>

typedef __bf16 bf16x8 __attribute__((ext_vector_type(8)));
typedef float  f32x4  __attribute__((ext_vector_type(4)));
typedef unsigned short ushort_t;
static_assert(sizeof(bf16x8) == 16, "bf16x8 must be 16B");

#define DEV __device__ __forceinline__

DEV f32x4 mfma16(bf16x8 a, bf16x8 b, f32x4 c) {
    return __builtin_amdgcn_mfma_f32_16x16x32_bf16(a, b, c, 0, 0, 0);
}
DEV float wsum(float v) {
#pragma unroll
    for (int o = 32; o > 0; o >>= 1) v += __shfl_xor(v, o, 64);
    return v;
}
DEV float wmaxr(float v) {
#pragma unroll
    for (int o = 32; o > 0; o >>= 1) v = fmaxf(v, __shfl_xor(v, o, 64));
    return v;
}
DEV float sigm(float x)   { return 1.0f / (1.0f + __expf(-x)); }
DEV float tanh_f(float x) { return 2.0f / (1.0f + __expf(-2.0f * x)) - 1.0f; }

// ---------------- dtype detection: 1 = inputs are bf16, 0 = inputs are fp32 --
__global__ __launch_bounds__(128) void kdetect(const unsigned int* __restrict__ raw,
                                               int* __restrict__ mode) {
    __shared__ int cnt;
    if (threadIdx.x == 0) cnt = 0;
    __syncthreads();
    unsigned int w = raw[threadIdx.x];
    unsigned short lo = (unsigned short)(w & 0xFFFFu);
    unsigned int f32bits = ((unsigned int)lo) << 16;
    float v;
    __builtin_memcpy(&v, &f32bits, 4);
    float a = fabsf(v);
    if (a >= 1e-4f && a <= 1.0f) atomicAdd(&cnt, 1);
    __syncthreads();
    if (threadIdx.x == 0) *mode = (cnt >= 64) ? 1 : 0;
}

// ---------------- convert raw float input -> bf16 ws copy --------------------
__global__ __launch_bounds__(256) void kcvt_bf16(const void* __restrict__ src,
                                                 __hip_bfloat16* __restrict__ dst,
                                                 int n, const int* __restrict__ mode) {
    int i = blockIdx.x * 256 + threadIdx.x;
    if (i >= n) return;
    if (*mode) dst[i] = ((const __hip_bfloat16*)src)[i];
    else       dst[i] = __float2bfloat16(((const float*)src)[i]);
}

// ---------------- convert raw float input -> fp32 ws copy --------------------
__global__ __launch_bounds__(256) void kcvt_f32(const void* __restrict__ src,
                                                float* __restrict__ dst,
                                                int n, const int* __restrict__ mode) {
    int i = blockIdx.x * 256 + threadIdx.x;
    if (i >= n) return;
    if (*mode) dst[i] = __bfloat162float(((const __hip_bfloat16*)src)[i]);
    else       dst[i] = ((const float*)src)[i];
}

// --------- tiled transpose + convert: out_bf16[c][r] = (bf16)in[r][c] --------
__global__ __launch_bounds__(256) void ktranspose_cvt(const void* __restrict__ src,
                                                      __hip_bfloat16* __restrict__ out,
                                                      int R, int C,
                                                      const int* __restrict__ mode) {
    __shared__ float tile[64][65];
    int c0 = blockIdx.x * 64, r0 = blockIdx.y * 64;
    int tx = threadIdx.x & 63, ty = threadIdx.x >> 6;
    int m = *mode;
#pragma unroll
    for (int i = ty; i < 64; i += 4) {
        size_t ix = (size_t)(r0 + i) * C + (c0 + tx);
        tile[i][tx] = m ? __bfloat162float(((const __hip_bfloat16*)src)[ix])
                        : ((const float*)src)[ix];
    }
    __syncthreads();
#pragma unroll
    for (int i = ty; i < 64; i += 4)
        out[(size_t)(c0 + i) * R + (r0 + tx)] = __float2bfloat16(tile[tx][i]);
}

// ---------------- prep: G tables  G[dir*2+half][v][j] = E @ Wi_half (+bias) --
__global__ __launch_bounds__(256) void kprep_gtab(
    const __hip_bfloat16* __restrict__ E,    // [128][128]
    const __hip_bfloat16* __restrict__ WiT,  // [2][2048][256]
    const float* __restrict__ bF,
    const float* __restrict__ bB,
    float* __restrict__ G)                   // [4][128][2048]
{
    int dh = blockIdx.x >> 6;            // 0..3 = dir*2+half
    int dir = dh >> 1, half = dh & 1;
    int m0 = ((blockIdx.x >> 5) & 1) * 64;
    int n0 = (blockIdx.x & 31) * 64;
    int lane = threadIdx.x & 63, wid = threadIdx.x >> 6;
    int wrow = wid >> 1, wcol = wid & 1;
    int r16 = lane & 15, quad = lane >> 4;

    f32x4 acc[2][2] = {};
    const __hip_bfloat16* Ap = E + (size_t)(m0 + wrow * 32 + r16) * 128 + quad * 8;
    const __hip_bfloat16* Bp = WiT + (size_t)dir * 2048 * 256
                             + (size_t)(n0 + wcol * 32 + r16) * 256 + half * 128 + quad * 8;
#pragma unroll
    for (int kb = 0; kb < 128; kb += 32) {
        bf16x8 a0 = *(const bf16x8*)(Ap + kb);
        bf16x8 a1 = *(const bf16x8*)(Ap + 16 * 128 + kb);
        bf16x8 b0 = *(const bf16x8*)(Bp + kb);
        bf16x8 b1 = *(const bf16x8*)(Bp + 16 * 256 + kb);
        acc[0][0] = mfma16(a0, b0, acc[0][0]);
        acc[0][1] = mfma16(a0, b1, acc[0][1]);
        acc[1][0] = mfma16(a1, b0, acc[1][0]);
        acc[1][1] = mfma16(a1, b1, acc[1][1]);
    }
    const float* bias = dir ? bB : bF;
    float* Gt = G + (size_t)dh * 128 * 2048;
#pragma unroll
    for (int rt = 0; rt < 2; rt++)
#pragma unroll
        for (int ct = 0; ct < 2; ct++)
#pragma unroll
            for (int r = 0; r < 4; r++) {
                int mm = m0 + wrow * 32 + rt * 16 + quad * 4 + r;
                int j = n0 + wcol * 32 + ct * 16 + r16;
                float v = acc[rt][ct][r];
                if (half == 0) v += bias[j];
                Gt[(size_t)mm * 2048 + j] = v;
            }
}

// ---------------- prep: VX[t][j] = field_emb @ v_Wi + v_b --------------------
__global__ __launch_bounds__(256) void kprep_vx(
    const __hip_bfloat16* __restrict__ fe,    // [32][1024]
    const __hip_bfloat16* __restrict__ vWiT,  // [4096][1024]
    const float* __restrict__ vb,             // [4096]
    float* __restrict__ VX)                   // [32][4096]
{
    int n0 = blockIdx.x * 128;
    int lane = threadIdx.x & 63, wid = threadIdx.x >> 6;
    int r16 = lane & 15, quad = lane >> 4;
    f32x4 acc[2][2] = {};
    const __hip_bfloat16* Ap = fe + (size_t)r16 * 1024 + quad * 8;
    const __hip_bfloat16* Bp = vWiT + (size_t)(n0 + wid * 32 + r16) * 1024 + quad * 8;
    for (int kb = 0; kb < 1024; kb += 32) {
        bf16x8 a0 = *(const bf16x8*)(Ap + kb);
        bf16x8 a1 = *(const bf16x8*)(Ap + 16 * 1024 + kb);
        bf16x8 b0 = *(const bf16x8*)(Bp + kb);
        bf16x8 b1 = *(const bf16x8*)(Bp + 16 * 1024 + kb);
        acc[0][0] = mfma16(a0, b0, acc[0][0]);
        acc[0][1] = mfma16(a0, b1, acc[0][1]);
        acc[1][0] = mfma16(a1, b0, acc[1][0]);
        acc[1][1] = mfma16(a1, b1, acc[1][1]);
    }
#pragma unroll
    for (int rt = 0; rt < 2; rt++)
#pragma unroll
        for (int ct = 0; ct < 2; ct++)
#pragma unroll
            for (int r = 0; r < 4; r++) {
                int m = rt * 16 + quad * 4 + r;             // t index < 32
                int j = n0 + wid * 32 + ct * 16 + r16;
                VX[(size_t)m * 4096 + j] = acc[rt][ct][r] + vb[j];
            }
}

// ---------------- encoder LSTM step (both dirs), fused gate update -----------
__global__ __launch_bounds__(256) void kenc_step(
    int t,
    const __hip_bfloat16* __restrict__ WhT,   // [2][2048][512]
    const float* __restrict__ Gtab,           // [4][128][2048]
    const int* __restrict__ exs,              // [64][1024]
    const int* __restrict__ cls,
    const __hip_bfloat16* __restrict__ h_in,  // [2][1024][512]
    __hip_bfloat16* __restrict__ h_out,       // [2][1024][512]
    float* __restrict__ c_st,                 // [2][1024][512]
    __hip_bfloat16* __restrict__ ctx)         // [64][256][4][1024]
{
    int bid = blockIdx.x;
    int dir = bid >> 7;
    int mt = (bid >> 3) & 15;
    int ut = bid & 7;
    int l = dir ? (63 - t) : t;
    int m0 = mt * 64, u0 = ut * 64;

    int lane = threadIdx.x & 63, wid = threadIdx.x >> 6;
    int wrow = wid >> 1, wcol = wid & 1;
    int r16 = lane & 15, quad = lane >> 4;

    f32x4 acc[4][2][2] = {};  // [gate][rowtile][coltile]

    const __hip_bfloat16* hA = h_in + (size_t)dir * 1024 * 512;
    const __hip_bfloat16* W  = WhT + (size_t)dir * 2048 * 512;
    const __hip_bfloat16* Ap = hA + (size_t)(m0 + wrow * 32 + r16) * 512 + quad * 8;
    int bcol = u0 + wcol * 32 + r16;

    for (int kb = 0; kb < 512; kb += 32) {
        bf16x8 a0 = *(const bf16x8*)(Ap + kb);
        bf16x8 a1 = *(const bf16x8*)(Ap + 16 * 512 + kb);
#pragma unroll
        for (int g = 0; g < 4; g++) {
#pragma unroll
            for (int ct = 0; ct < 2; ct++) {
                bf16x8 bv = *(const bf16x8*)(W + (size_t)(g * 512 + bcol + ct * 16) * 512 + kb + quad * 8);
                acc[g][0][ct] = mfma16(a0, bv, acc[g][0][ct]);
                acc[g][1][ct] = mfma16(a1, bv, acc[g][1][ct]);
            }
        }
    }

    const float* Ge = Gtab + (size_t)dir * 2 * 128 * 2048;
    const float* Gc = Ge + 128 * 2048;

#pragma unroll
    for (int rt = 0; rt < 2; rt++) {
#pragma unroll
        for (int r = 0; r < 4; r++) {
            int m = m0 + wrow * 32 + rt * 16 + quad * 4 + r;
            const float* ge = Ge + (size_t)exs[l * 1024 + m] * 2048;
            const float* gc = Gc + (size_t)cls[l * 1024 + m] * 2048;
#pragma unroll
            for (int ct = 0; ct < 2; ct++) {
                int u = u0 + wcol * 32 + ct * 16 + r16;
                float gi = acc[0][rt][ct][r] + ge[u]        + gc[u];
                float gf = acc[1][rt][ct][r] + ge[512 + u]  + gc[512 + u];
                float gg = acc[2][rt][ct][r] + ge[1024 + u] + gc[1024 + u];
                float go = acc[3][rt][ct][r] + ge[1536 + u] + gc[1536 + u];
                size_t cix = (size_t)dir * 1024 * 512 + (size_t)m * 512 + u;
                float cn = sigm(gf) * c_st[cix] + sigm(gi) * tanh_f(gg);
                c_st[cix] = cn;
                float hn = sigm(go) * tanh_f(cn);
                __hip_bfloat16 hb = __float2bfloat16(hn);
                h_out[cix] = hb;
                int bb = m >> 2, nn = m & 3;
                ctx[(((size_t)l * 256 + bb) * 4 + nn) * 1024 + dir * 512 + u] = hb;
            }
        }
    }
}

// ---------------- decoder: q = h @ W_attn ------------------------------------
__global__ __launch_bounds__(256) void kqgemm(
    const __hip_bfloat16* __restrict__ A,   // [256][1024]
    const __hip_bfloat16* __restrict__ BT,  // [1024][1024]
    float* __restrict__ C)                  // [256][1024]
{
    int m0 = (blockIdx.x >> 4) * 64;
    int n0 = (blockIdx.x & 15) * 64;
    int lane = threadIdx.x & 63, wid = threadIdx.x >> 6;
    int wrow = wid >> 1, wcol = wid & 1;
    int r16 = lane & 15, quad = lane >> 4;
    f32x4 acc[2][2] = {};
    const __hip_bfloat16* Ap = A + (size_t)(m0 + wrow * 32 + r16) * 1024 + quad * 8;
    const __hip_bfloat16* Bp = BT + (size_t)(n0 + wcol * 32 + r16) * 1024 + quad * 8;
    for (int kb = 0; kb < 1024; kb += 32) {
        bf16x8 a0 = *(const bf16x8*)(Ap + kb);
        bf16x8 a1 = *(const bf16x8*)(Ap + 16 * 1024 + kb);
        bf16x8 b0 = *(const bf16x8*)(Bp + kb);
        bf16x8 b1 = *(const bf16x8*)(Bp + 16 * 1024 + kb);
        acc[0][0] = mfma16(a0, b0, acc[0][0]);
        acc[0][1] = mfma16(a0, b1, acc[0][1]);
        acc[1][0] = mfma16(a1, b0, acc[1][0]);
        acc[1][1] = mfma16(a1, b1, acc[1][1]);
    }
#pragma unroll
    for (int rt = 0; rt < 2; rt++)
#pragma unroll
        for (int ct = 0; ct < 2; ct++)
#pragma unroll
            for (int r = 0; r < 4; r++) {
                int m = m0 + wrow * 32 + rt * 16 + quad * 4 + r;
                int nn = n0 + wcol * 32 + ct * 16 + r16;
                C[(size_t)m * 1024 + nn] = acc[rt][ct][r];
            }
}

// ------ decoder: attention (online softmax) + max-pool + logits + NLL --------
__global__ __launch_bounds__(256) void kattn(
    int t,
    const float* __restrict__ q,             // [256][1024]
    const __hip_bfloat16* __restrict__ ctx,  // [64][256][4][1024]
    const __hip_bfloat16* __restrict__ hcur, // [256][1024]
    const __hip_bfloat16* __restrict__ WcT,  // [64][2048]
    const float* __restrict__ bcomp,         // [64]
    const int* __restrict__ actions,         // [256][32]
    float* __restrict__ nll)                 // [256]
{
    int b = blockIdx.x;
    int tid = threadIdx.x;
    int lane = tid & 63, n = tid >> 6;       // wave n handles io example n

    float qr[16];
    const float* qp = q + (size_t)b * 1024 + lane * 16;
#pragma unroll
    for (int i = 0; i < 16; i++) qr[i] = qp[i];

    float mx = -1e30f, ssum = 0.f;
    float cacc[16];
#pragma unroll
    for (int i = 0; i < 16; i++) cacc[i] = 0.f;

    const __hip_bfloat16* cb = ctx + ((size_t)b * 4 + n) * 1024 + lane * 16;
    for (int l = 0; l < 64; l++) {
        const __hip_bfloat16* row = cb + (size_t)l * (1024 * 1024);
        bf16x8 v0 = *(const bf16x8*)(row);
        bf16x8 v1 = *(const bf16x8*)(row + 8);
        float rv[16];
#pragma unroll
        for (int i = 0; i < 8; i++) { rv[i] = (float)v0[i]; rv[8 + i] = (float)v1[i]; }
        float s = 0.f;
#pragma unroll
        for (int i = 0; i < 16; i++) s += rv[i] * qr[i];
        s = wsum(s);
        float mn = fmaxf(mx, s);
        float sc = __expf(mx - mn);
        float p  = __expf(s - mn);
        ssum = ssum * sc + p;
#pragma unroll
        for (int i = 0; i < 16; i++) cacc[i] = cacc[i] * sc + p * rv[i];
        mx = mn;
    }

    __shared__ float ctxn[4][1024];
    __shared__ float hb[1024];
    __shared__ float lg[64];
    float inv = 1.f / ssum;
#pragma unroll
    for (int i = 0; i < 16; i++) ctxn[n][lane * 16 + i] = cacc[i] * inv;
    for (int e = tid; e < 1024; e += 256) hb[e] = __bfloat162float(hcur[(size_t)b * 1024 + e]);
    __syncthreads();
    for (int e = tid; e < 1024; e += 256)
        ctxn[0][e] = fmaxf(fmaxf(ctxn[0][e], ctxn[1][e]), fmaxf(ctxn[2][e], ctxn[3][e]));
    __syncthreads();

    // logits: wave n computes prods n*16 .. n*16+15
    for (int pp = 0; pp < 16; pp++) {
        int p = n * 16 + pp;
        const __hip_bfloat16* wr = WcT + (size_t)p * 2048;
        float s = 0.f;
#pragma unroll
        for (int j = 0; j < 16; j++) {
            int e = lane + j * 64;
            s += hb[e] * __bfloat162float(wr[e]);
            s += ctxn[0][e] * __bfloat162float(wr[1024 + e]);
        }
        s = wsum(s);
        if (lane == 0) lg[p] = s + bcomp[p];
    }
    __syncthreads();
    if (tid < 64) {
        float v = lg[tid];
        float m2 = wmaxr(v);
        float se = wsum(__expf(v - m2));
        int a = actions[b * 32 + t];
        if (tid == a) nll[b] -= (v - m2 - __logf(se));
    }
}

// ---------------- decoder: v-LSTM cell, fused update -------------------------
__global__ __launch_bounds__(256) void kcell(
    int t,
    const __hip_bfloat16* __restrict__ vWhT,  // [4096][1024]
    const float* __restrict__ VX,             // [32][4096]
    const __hip_bfloat16* __restrict__ h_in,  // [256][1024]
    __hip_bfloat16* __restrict__ h_out,       // [256][1024]
    float* __restrict__ c_st)                 // [256][1024]
{
    int m0 = (blockIdx.x >> 4) * 64;
    int u0 = (blockIdx.x & 15) * 64;
    int lane = threadIdx.x & 63, wid = threadIdx.x >> 6;
    int wrow = wid >> 1, wcol = wid & 1;
    int r16 = lane & 15, quad = lane >> 4;

    f32x4 acc[4][2][2] = {};
    const __hip_bfloat16* Ap = h_in + (size_t)(m0 + wrow * 32 + r16) * 1024 + quad * 8;
    int bcol = u0 + wcol * 32 + r16;

    for (int kb = 0; kb < 1024; kb += 32) {
        bf16x8 a0 = *(const bf16x8*)(Ap + kb);
        bf16x8 a1 = *(const bf16x8*)(Ap + 16 * 1024 + kb);
#pragma unroll
        for (int g = 0; g < 4; g++) {
#pragma unroll
            for (int ct = 0; ct < 2; ct++) {
                bf16x8 bv = *(const bf16x8*)(vWhT + (size_t)(g * 1024 + bcol + ct * 16) * 1024 + kb + quad * 8);
                acc[g][0][ct] = mfma16(a0, bv, acc[g][0][ct]);
                acc[g][1][ct] = mfma16(a1, bv, acc[g][1][ct]);
            }
        }
    }
    const float* vx = VX + (size_t)t * 4096;
#pragma unroll
    for (int rt = 0; rt < 2; rt++)
#pragma unroll
        for (int r = 0; r < 4; r++) {
            int m = m0 + wrow * 32 + rt * 16 + quad * 4 + r;
#pragma unroll
            for (int ct = 0; ct < 2; ct++) {
                int u = u0 + wcol * 32 + ct * 16 + r16;
                float gi = acc[0][rt][ct][r] + vx[u];
                float gf = acc[1][rt][ct][r] + vx[1024 + u];
                float gg = acc[2][rt][ct][r] + vx[2048 + u];
                float go = acc[3][rt][ct][r] + vx[3072 + u];
                size_t cix = (size_t)m * 1024 + u;
                float cn = sigm(gf) * c_st[cix] + sigm(gi) * tanh_f(gg);
                c_st[cix] = cn;
                h_out[cix] = __float2bfloat16(sigm(go) * tanh_f(cn));
            }
        }
}

// ---------------- decoder init: max-pool final states over io examples -------
__global__ __launch_bounds__(256) void kinit_dec(
    const __hip_bfloat16* __restrict__ hf,  // final h (buf0): [2][1024][512]
    const float* __restrict__ cf,           // final c: [2][1024][512]
    __hip_bfloat16* __restrict__ h0,        // [256][1024]
    float* __restrict__ c0)                 // [256][1024]
{
    int idx = blockIdx.x * 256 + threadIdx.x;  // < 262144
    int b = idx >> 10, e = idx & 1023;
    int dir = e >> 9, u = e & 511;
    const __hip_bfloat16* hs = hf + (size_t)dir * 1024 * 512;
    const float* cs = cf + (size_t)dir * 1024 * 512;
    float hv = -3.4e38f, cv = -3.4e38f;
#pragma unroll
    for (int n = 0; n < 4; n++) {
        size_t ix = (size_t)(b * 4 + n) * 512 + u;
        hv = fmaxf(hv, __bfloat162float(hs[ix]));
        cv = fmaxf(cv, cs[ix]);
    }
    h0[idx] = __float2bfloat16(hv);
    c0[idx] = cv;
}

__global__ void kfinal(const float* __restrict__ nll, void* __restrict__ out,
                       const int* __restrict__ mode) {
    int i = threadIdx.x;
    if (*mode) ((__hip_bfloat16*)out)[i] = __float2bfloat16(nll[i]);
    else       ((float*)out)[i] = nll[i];
}

// -----------------------------------------------------------------------------
extern "C" void kernel_launch(void* const* d_in, const int* in_sizes, int n_in,
                              void* d_out, int out_size, void* d_ws, size_t ws_size,
                              hipStream_t stream) {
    const int* exs = (const int*)d_in[0];
    const int* cls = (const int*)d_in[1];
    const void* E_raw     = d_in[2];
    const void* WiF_raw   = d_in[3];
    const void* WhF_raw   = d_in[4];
    const void* bF_raw    = d_in[5];
    const void* WiB_raw   = d_in[6];
    const void* WhB_raw   = d_in[7];
    const void* bB_raw    = d_in[8];
    const void* Wattn_raw = d_in[9];
    const void* Wcomp_raw = d_in[10];
    const void* bcomp_raw = d_in[11];
    const void* vWi_raw   = d_in[12];
    const void* vWh_raw   = d_in[13];
    const void* vb_raw    = d_in[14];
    const void* fe_raw    = d_in[15];
    const int* actions = (const int*)d_in[16];
    (void)in_sizes; (void)n_in; (void)out_size; (void)ws_size;

    char* w = (char*)d_ws;
    size_t off = 0;
    auto take = [&](size_t bytes) -> char* {
        char* p = w + off;
        off = (off + bytes + 255) & ~(size_t)255;
        return p;
    };
    __hip_bfloat16* WhT    = (__hip_bfloat16*)take(2ull * 2048 * 512 * 2);
    __hip_bfloat16* WiT    = (__hip_bfloat16*)take(2ull * 2048 * 256 * 2);
    __hip_bfloat16* vWhT   = (__hip_bfloat16*)take(4096ull * 1024 * 2);
    __hip_bfloat16* vWiT   = (__hip_bfloat16*)take(4096ull * 1024 * 2);
    __hip_bfloat16* WattnT = (__hip_bfloat16*)take(1024ull * 1024 * 2);
    __hip_bfloat16* WcT    = (__hip_bfloat16*)take(64ull * 2048 * 2);
    __hip_bfloat16* Ebf    = (__hip_bfloat16*)take(128ull * 128 * 2);
    __hip_bfloat16* febf   = (__hip_bfloat16*)take(32ull * 1024 * 2);
    float* bFf   = (float*)take(2048 * 4);
    float* bBf   = (float*)take(2048 * 4);
    float* bcf   = (float*)take(64 * 4);
    float* vbf   = (float*)take(4096 * 4);
    float* Gtab  = (float*)take(4ull * 128 * 2048 * 4);
    float* VX    = (float*)take(32ull * 4096 * 4);
    __hip_bfloat16* hEnc = (__hip_bfloat16*)take(2ull * 2 * 1024 * 512 * 2); // [buf][dir][1024][512]
    float* cEnc = (float*)take(2ull * 1024 * 512 * 4);
    __hip_bfloat16* hDec = (__hip_bfloat16*)take(2ull * 256 * 1024 * 2);
    float* cDec = (float*)take(256ull * 1024 * 4);
    float* qbuf = (float*)take(256ull * 1024 * 4);
    float* nll  = (float*)take(256 * 4);
    int*   mode = (int*)take(256);
    __hip_bfloat16* ctx  = (__hip_bfloat16*)take(64ull * 1024 * 1024 * 2);   // [64][256][4][1024]

    // zero-init state (ws is re-poisoned 0xAA before every call)
    hipMemsetAsync(hEnc, 0, 2ull * 1024 * 512 * 2, stream);  // h buf0, both dirs
    hipMemsetAsync(cEnc, 0, 2ull * 1024 * 512 * 4, stream);
    hipMemsetAsync(nll, 0, 256 * 4, stream);

    // dtype detection off E_io's raw words
    kdetect<<<1, 128, 0, stream>>>((const unsigned int*)E_raw, mode);

    // plain converts
    kcvt_bf16<<<64, 256, 0, stream>>>(E_raw,  Ebf,  128 * 128, mode);
    kcvt_bf16<<<128, 256, 0, stream>>>(fe_raw, febf, 32 * 1024, mode);
    kcvt_f32<<<8, 256, 0, stream>>>(bF_raw, bFf, 2048, mode);
    kcvt_f32<<<8, 256, 0, stream>>>(bB_raw, bBf, 2048, mode);
    kcvt_f32<<<1, 256, 0, stream>>>(bcomp_raw, bcf, 64, mode);
    kcvt_f32<<<16, 256, 0, stream>>>(vb_raw, vbf, 4096, mode);

    // weight transposes + convert (B-operand wants [n][k] contiguous-k rows)
    ktranspose_cvt<<<dim3(32, 8),  256, 0, stream>>>(WhF_raw,   WhT,              512, 2048, mode);
    ktranspose_cvt<<<dim3(32, 8),  256, 0, stream>>>(WhB_raw,   WhT + 2048 * 512, 512, 2048, mode);
    ktranspose_cvt<<<dim3(32, 4),  256, 0, stream>>>(WiF_raw,   WiT,              256, 2048, mode);
    ktranspose_cvt<<<dim3(32, 4),  256, 0, stream>>>(WiB_raw,   WiT + 2048 * 256, 256, 2048, mode);
    ktranspose_cvt<<<dim3(64, 16), 256, 0, stream>>>(vWh_raw,   vWhT,            1024, 4096, mode);
    ktranspose_cvt<<<dim3(64, 16), 256, 0, stream>>>(vWi_raw,   vWiT,            1024, 4096, mode);
    ktranspose_cvt<<<dim3(16, 16), 256, 0, stream>>>(Wattn_raw, WattnT,          1024, 1024, mode);
    ktranspose_cvt<<<dim3(1, 32),  256, 0, stream>>>(Wcomp_raw, WcT,             2048, 64,   mode);

    kprep_gtab<<<256, 256, 0, stream>>>(Ebf, WiT, bFf, bBf, Gtab);
    kprep_vx<<<32, 256, 0, stream>>>(febf, vWiT, vbf, VX);

    const size_t HB = 2ull * 1024 * 512;   // elements per h_enc buffer
    for (int t = 0; t < 64; t++) {
        kenc_step<<<256, 256, 0, stream>>>(t, WhT, Gtab, exs, cls,
                                           hEnc + (size_t)(t & 1) * HB,
                                           hEnc + (size_t)((t + 1) & 1) * HB,
                                           cEnc, ctx);
    }
    kinit_dec<<<1024, 256, 0, stream>>>(hEnc /*finals land in buf0*/, cEnc, hDec, cDec);

    const size_t HD = 256ull * 1024;
    for (int t = 0; t < 32; t++) {
        const __hip_bfloat16* hcur = hDec + (size_t)(t & 1) * HD;
        kqgemm<<<64, 256, 0, stream>>>(hcur, WattnT, qbuf);
        kattn<<<256, 256, 0, stream>>>(t, qbuf, ctx, hcur, WcT, bcf, actions, nll);
        kcell<<<64, 256, 0, stream>>>(t, vWhT, VX, hcur, hDec + (size_t)((t + 1) & 1) * HD, cDec);
    }
    kfinal<<<1, 256, 0, stream>>>(nll, d_out, mode);
}

// Round 3
// 3241.382 us; speedup vs baseline: 2.2910x; 2.2910x over previous
//
#include <hip/hip_runtime.h>
#include <hip/hip_bf16.h>

typedef __bf16 bf16x8 __attribute__((ext_vector_type(8)));
typedef float  f32x4  __attribute__((ext_vector_type(4)));
typedef unsigned short ushort_t;
static_assert(sizeof(bf16x8) == 16, "bf16x8 must be 16B");

#define DEV __device__ __forceinline__

DEV f32x4 mfma16(bf16x8 a, bf16x8 b, f32x4 c) {
    return __builtin_amdgcn_mfma_f32_16x16x32_bf16(a, b, c, 0, 0, 0);
}
DEV float wsum(float v) {
#pragma unroll
    for (int o = 32; o > 0; o >>= 1) v += __shfl_xor(v, o, 64);
    return v;
}
DEV float wmaxr(float v) {
#pragma unroll
    for (int o = 32; o > 0; o >>= 1) v = fmaxf(v, __shfl_xor(v, o, 64));
    return v;
}
DEV float sigm(float x)   { return 1.0f / (1.0f + __expf(-x)); }
DEV float tanh_f(float x) { return 2.0f / (1.0f + __expf(-2.0f * x)) - 1.0f; }

// async global->LDS, 16B per lane; lds dest must be wave-uniform base (+lane*16)
DEV void glds16(const __hip_bfloat16* g, __hip_bfloat16* l) {
    __builtin_amdgcn_global_load_lds(
        (const __attribute__((address_space(1))) unsigned int*)g,
        (__attribute__((address_space(3))) unsigned int*)l, 16, 0, 0);
}

// ---------------- dtype detection: 1 = inputs are bf16, 0 = inputs are fp32 --
__global__ __launch_bounds__(128) void kdetect(const unsigned int* __restrict__ raw,
                                               int* __restrict__ mode) {
    __shared__ int cnt;
    if (threadIdx.x == 0) cnt = 0;
    __syncthreads();
    unsigned int w = raw[threadIdx.x];
    unsigned short lo = (unsigned short)(w & 0xFFFFu);
    unsigned int f32bits = ((unsigned int)lo) << 16;
    float v;
    __builtin_memcpy(&v, &f32bits, 4);
    float a = fabsf(v);
    if (a >= 1e-4f && a <= 1.0f) atomicAdd(&cnt, 1);
    __syncthreads();
    if (threadIdx.x == 0) *mode = (cnt >= 64) ? 1 : 0;
}

__global__ __launch_bounds__(256) void kcvt_bf16(const void* __restrict__ src,
                                                 __hip_bfloat16* __restrict__ dst,
                                                 int n, const int* __restrict__ mode) {
    int i = blockIdx.x * 256 + threadIdx.x;
    if (i >= n) return;
    if (*mode) dst[i] = ((const __hip_bfloat16*)src)[i];
    else       dst[i] = __float2bfloat16(((const float*)src)[i]);
}

__global__ __launch_bounds__(256) void kcvt_f32(const void* __restrict__ src,
                                                float* __restrict__ dst,
                                                int n, const int* __restrict__ mode) {
    int i = blockIdx.x * 256 + threadIdx.x;
    if (i >= n) return;
    if (*mode) dst[i] = __bfloat162float(((const __hip_bfloat16*)src)[i]);
    else       dst[i] = ((const float*)src)[i];
}

// --------- tiled transpose + convert: out_bf16[c][r] = (bf16)in[r][c] --------
__global__ __launch_bounds__(256) void ktranspose_cvt(const void* __restrict__ src,
                                                      __hip_bfloat16* __restrict__ out,
                                                      int R, int C,
                                                      const int* __restrict__ mode) {
    __shared__ float tile[64][65];
    int c0 = blockIdx.x * 64, r0 = blockIdx.y * 64;
    int tx = threadIdx.x & 63, ty = threadIdx.x >> 6;
    int m = *mode;
#pragma unroll
    for (int i = ty; i < 64; i += 4) {
        size_t ix = (size_t)(r0 + i) * C + (c0 + tx);
        tile[i][tx] = m ? __bfloat162float(((const __hip_bfloat16*)src)[ix])
                        : ((const float*)src)[ix];
    }
    __syncthreads();
#pragma unroll
    for (int i = ty; i < 64; i += 4)
        out[(size_t)(c0 + i) * R + (r0 + tx)] = __float2bfloat16(tile[tx][i]);
}

// ---------------- prep: G tables  G[dir*2+half][v][j] = E @ Wi_half (+bias) --
__global__ __launch_bounds__(256) void kprep_gtab(
    const __hip_bfloat16* __restrict__ E,    // [128][128]
    const __hip_bfloat16* __restrict__ WiT,  // [2][2048][256]
    const float* __restrict__ bF,
    const float* __restrict__ bB,
    float* __restrict__ G)                   // [4][128][2048]
{
    int dh = blockIdx.x >> 6;
    int dir = dh >> 1, half = dh & 1;
    int m0 = ((blockIdx.x >> 5) & 1) * 64;
    int n0 = (blockIdx.x & 31) * 64;
    int lane = threadIdx.x & 63, wid = threadIdx.x >> 6;
    int wrow = wid >> 1, wcol = wid & 1;
    int r16 = lane & 15, quad = lane >> 4;

    f32x4 acc[2][2] = {};
    const __hip_bfloat16* Ap = E + (size_t)(m0 + wrow * 32 + r16) * 128 + quad * 8;
    const __hip_bfloat16* Bp = WiT + (size_t)dir * 2048 * 256
                             + (size_t)(n0 + wcol * 32 + r16) * 256 + half * 128 + quad * 8;
#pragma unroll
    for (int kb = 0; kb < 128; kb += 32) {
        bf16x8 a0 = *(const bf16x8*)(Ap + kb);
        bf16x8 a1 = *(const bf16x8*)(Ap + 16 * 128 + kb);
        bf16x8 b0 = *(const bf16x8*)(Bp + kb);
        bf16x8 b1 = *(const bf16x8*)(Bp + 16 * 256 + kb);
        acc[0][0] = mfma16(a0, b0, acc[0][0]);
        acc[0][1] = mfma16(a0, b1, acc[0][1]);
        acc[1][0] = mfma16(a1, b0, acc[1][0]);
        acc[1][1] = mfma16(a1, b1, acc[1][1]);
    }
    const float* bias = dir ? bB : bF;
    float* Gt = G + (size_t)dh * 128 * 2048;
#pragma unroll
    for (int rt = 0; rt < 2; rt++)
#pragma unroll
        for (int ct = 0; ct < 2; ct++)
#pragma unroll
            for (int r = 0; r < 4; r++) {
                int mm = m0 + wrow * 32 + rt * 16 + quad * 4 + r;
                int j = n0 + wcol * 32 + ct * 16 + r16;
                float v = acc[rt][ct][r];
                if (half == 0) v += bias[j];
                Gt[(size_t)mm * 2048 + j] = v;
            }
}

// ---------------- prep: VX[t][j] = field_emb @ v_Wi + v_b --------------------
__global__ __launch_bounds__(256) void kprep_vx(
    const __hip_bfloat16* __restrict__ fe,    // [32][1024]
    const __hip_bfloat16* __restrict__ vWiT,  // [4096][1024]
    const float* __restrict__ vb,             // [4096]
    float* __restrict__ VX)                   // [32][4096]
{
    int n0 = blockIdx.x * 128;
    int lane = threadIdx.x & 63, wid = threadIdx.x >> 6;
    int r16 = lane & 15, quad = lane >> 4;
    f32x4 acc[2][2] = {};
    const __hip_bfloat16* Ap = fe + (size_t)r16 * 1024 + quad * 8;
    const __hip_bfloat16* Bp = vWiT + (size_t)(n0 + wid * 32 + r16) * 1024 + quad * 8;
    for (int kb = 0; kb < 1024; kb += 32) {
        bf16x8 a0 = *(const bf16x8*)(Ap + kb);
        bf16x8 a1 = *(const bf16x8*)(Ap + 16 * 1024 + kb);
        bf16x8 b0 = *(const bf16x8*)(Bp + kb);
        bf16x8 b1 = *(const bf16x8*)(Bp + 16 * 1024 + kb);
        acc[0][0] = mfma16(a0, b0, acc[0][0]);
        acc[0][1] = mfma16(a0, b1, acc[0][1]);
        acc[1][0] = mfma16(a1, b0, acc[1][0]);
        acc[1][1] = mfma16(a1, b1, acc[1][1]);
    }
#pragma unroll
    for (int rt = 0; rt < 2; rt++)
#pragma unroll
        for (int ct = 0; ct < 2; ct++)
#pragma unroll
            for (int r = 0; r < 4; r++) {
                int m = rt * 16 + quad * 4 + r;
                int j = n0 + wid * 32 + ct * 16 + r16;
                VX[(size_t)m * 4096 + j] = acc[rt][ct][r] + vb[j];
            }
}

// ======== encoder LSTM step: LDS-staged, dbuf, fused gates ===================
// grid 256: dir(2) x mt(16, 64 rows) x us(8, 64 u-cols). 4 waves: wave w owns
// u-cols [u0+w*16, u0+w*16+16) for all 4 gates, 64 m rows. BK=64, K=512.
__global__ __launch_bounds__(256, 2) void kenc_step(
    int t,
    const __hip_bfloat16* __restrict__ WhT,   // [2][2048][512]
    const float* __restrict__ Gtab,           // [4][128][2048]
    const int* __restrict__ exs,
    const int* __restrict__ cls,
    const __hip_bfloat16* __restrict__ h_in,  // [2][1024][512]
    __hip_bfloat16* __restrict__ h_out,
    float* __restrict__ c_st,                 // [2][1024][512]
    __hip_bfloat16* __restrict__ ctx)         // [64][256][4][1024]
{
    __shared__ __align__(16) __hip_bfloat16 sA[2][64 * 64];
    __shared__ __align__(16) __hip_bfloat16 sB[2][256 * 64];

    int bid = blockIdx.x;
    int dir = bid >> 7;
    int mt  = (bid >> 3) & 15;
    int us  = bid & 7;
    int l = dir ? (63 - t) : t;
    int m0 = mt * 64, u0 = us * 64;

    int lane = threadIdx.x & 63, w = threadIdx.x >> 6;
    int r16 = lane & 15, quad = lane >> 4;
    int srow = lane >> 3, scol = (lane & 7) * 8;   // staging: 8 rows/call

    const __hip_bfloat16* Ab = h_in + (size_t)dir * 1024 * 512;
    const __hip_bfloat16* Bb = WhT + (size_t)dir * 2048 * 512;

    f32x4 acc[4][4] = {};  // [gate][mi]

    auto stage = [&](int buf, int it) {
        int kb = it * 64;
        // A: 64 rows x 64 k; wave w rows [w*16, w*16+16)
#pragma unroll
        for (int c = 0; c < 2; c++) {
            int rl = w * 16 + c * 8;
            glds16(Ab + (size_t)(m0 + rl + srow) * 512 + kb + scol,
                   &sA[buf][rl * 64]);
        }
        // B: 256 rows (4 gates x 64 u) x 64 k; wave w rows [w*64, w*64+64)
#pragma unroll
        for (int c = 0; c < 8; c++) {
            int rl = w * 64 + c * 8;
            int rr = rl + srow;
            int g = rr >> 6, j = rr & 63;
            glds16(Bb + (size_t)(g * 512 + u0 + j) * 512 + kb + scol,
                   &sB[buf][rl * 64]);
        }
    };

    stage(0, 0);
    __syncthreads();
    int buf = 0;
    const int NIT = 8;  // 512/64
    for (int it = 0; it < NIT; it++) {
        if (it + 1 < NIT) stage(buf ^ 1, it + 1);
#pragma unroll
        for (int k32 = 0; k32 < 64; k32 += 32) {
            bf16x8 a[4], bf[4];
#pragma unroll
            for (int mi = 0; mi < 4; mi++)
                a[mi] = *(const bf16x8*)&sA[buf][(mi * 16 + r16) * 64 + k32 + quad * 8];
#pragma unroll
            for (int g = 0; g < 4; g++)
                bf[g] = *(const bf16x8*)&sB[buf][(g * 64 + w * 16 + r16) * 64 + k32 + quad * 8];
#pragma unroll
            for (int g = 0; g < 4; g++)
#pragma unroll
                for (int mi = 0; mi < 4; mi++)
                    acc[g][mi] = mfma16(a[mi], bf[g], acc[g][mi]);
        }
        __syncthreads();
        buf ^= 1;
    }

    // epilogue: thread owns u = u0 + w*16 + r16, 16 m's
    int u = u0 + w * 16 + r16;
    size_t cbase = (size_t)dir * 1024 * 512;
    const float* GeT = Gtab + (size_t)(dir * 2) * 128 * 2048;
    const float* GcT = Gtab + (size_t)(dir * 2 + 1) * 128 * 2048;
#pragma unroll
    for (int mi = 0; mi < 4; mi++)
#pragma unroll
        for (int r = 0; r < 4; r++) {
            int m = m0 + mi * 16 + quad * 4 + r;
            const float* ge = GeT + (size_t)exs[l * 1024 + m] * 2048;
            const float* gc = GcT + (size_t)cls[l * 1024 + m] * 2048;
            float gi = acc[0][mi][r] + ge[u]        + gc[u];
            float gf = acc[1][mi][r] + ge[512 + u]  + gc[512 + u];
            float gg = acc[2][mi][r] + ge[1024 + u] + gc[1024 + u];
            float go = acc[3][mi][r] + ge[1536 + u] + gc[1536 + u];
            size_t cix = cbase + (size_t)m * 512 + u;
            float cn = sigm(gf) * c_st[cix] + sigm(gi) * tanh_f(gg);
            c_st[cix] = cn;
            float hn = sigm(go) * tanh_f(cn);
            __hip_bfloat16 hb = __float2bfloat16(hn);
            h_out[cix] = hb;
            ctx[(((size_t)l * 256 + (m >> 2)) * 4 + (m & 3)) * 1024 + dir * 512 + u] = hb;
        }
}

// ======== decoder fused GEMM: v-LSTM cell (blocks 0..63) + q-GEMM (64..127) ==
__global__ __launch_bounds__(256, 2) void kdec_gemm(
    int t,
    const __hip_bfloat16* __restrict__ vWhT,   // [4096][1024]
    const __hip_bfloat16* __restrict__ WattnT, // [1024][1024]
    const float* __restrict__ VX,              // [32][4096]
    const __hip_bfloat16* __restrict__ h_in,   // [256][1024]  (h_t)
    __hip_bfloat16* __restrict__ h_out,        // [256][1024]  (h_{t+1})
    float* __restrict__ c_st,                  // [256][1024]
    float* __restrict__ qout)                  // [256][1024]  (q_t)
{
    __shared__ __align__(16) __hip_bfloat16 sA[2][64 * 64];
    __shared__ __align__(16) __hip_bfloat16 sB[2][256 * 64];

    int bid = blockIdx.x;
    int lane = threadIdx.x & 63, w = threadIdx.x >> 6;
    int r16 = lane & 15, quad = lane >> 4;
    int srow = lane >> 3, scol = (lane & 7) * 8;
    const int NIT = 16;  // 1024/64

    if (bid < 64) {
        // ---- cell path: 64m x (4 gates x 64u) tile
        int m0 = (bid >> 4) * 64, u0 = (bid & 15) * 64;
        f32x4 acc[4][4] = {};
        auto stage = [&](int buf, int it) {
            int kb = it * 64;
#pragma unroll
            for (int c = 0; c < 2; c++) {
                int rl = w * 16 + c * 8;
                glds16(h_in + (size_t)(m0 + rl + srow) * 1024 + kb + scol,
                       &sA[buf][rl * 64]);
            }
#pragma unroll
            for (int c = 0; c < 8; c++) {
                int rl = w * 64 + c * 8;
                int rr = rl + srow;
                int g = rr >> 6, j = rr & 63;
                glds16(vWhT + (size_t)(g * 1024 + u0 + j) * 1024 + kb + scol,
                       &sB[buf][rl * 64]);
            }
        };
        stage(0, 0);
        __syncthreads();
        int buf = 0;
        for (int it = 0; it < NIT; it++) {
            if (it + 1 < NIT) stage(buf ^ 1, it + 1);
#pragma unroll
            for (int k32 = 0; k32 < 64; k32 += 32) {
                bf16x8 a[4], bf[4];
#pragma unroll
                for (int mi = 0; mi < 4; mi++)
                    a[mi] = *(const bf16x8*)&sA[buf][(mi * 16 + r16) * 64 + k32 + quad * 8];
#pragma unroll
                for (int g = 0; g < 4; g++)
                    bf[g] = *(const bf16x8*)&sB[buf][(g * 64 + w * 16 + r16) * 64 + k32 + quad * 8];
#pragma unroll
                for (int g = 0; g < 4; g++)
#pragma unroll
                    for (int mi = 0; mi < 4; mi++)
                        acc[g][mi] = mfma16(a[mi], bf[g], acc[g][mi]);
            }
            __syncthreads();
            buf ^= 1;
        }
        int u = u0 + w * 16 + r16;
        const float* vx = VX + (size_t)t * 4096;
        float v0 = vx[u], v1 = vx[1024 + u], v2 = vx[2048 + u], v3 = vx[3072 + u];
#pragma unroll
        for (int mi = 0; mi < 4; mi++)
#pragma unroll
            for (int r = 0; r < 4; r++) {
                int m = m0 + mi * 16 + quad * 4 + r;
                float gi = acc[0][mi][r] + v0;
                float gf = acc[1][mi][r] + v1;
                float gg = acc[2][mi][r] + v2;
                float go = acc[3][mi][r] + v3;
                size_t cix = (size_t)m * 1024 + u;
                float cn = sigm(gf) * c_st[cix] + sigm(gi) * tanh_f(gg);
                c_st[cix] = cn;
                h_out[cix] = __float2bfloat16(sigm(go) * tanh_f(cn));
            }
    } else {
        // ---- q path: plain 64m x 64n GEMM vs WattnT, fp32 out
        int b2 = bid - 64;
        int m0 = (b2 >> 4) * 64, n0 = (b2 & 15) * 64;
        f32x4 acc[4] = {};
        auto stage = [&](int buf, int it) {
            int kb = it * 64;
#pragma unroll
            for (int c = 0; c < 2; c++) {
                int rl = w * 16 + c * 8;
                glds16(h_in + (size_t)(m0 + rl + srow) * 1024 + kb + scol,
                       &sA[buf][rl * 64]);
                glds16(WattnT + (size_t)(n0 + rl + srow) * 1024 + kb + scol,
                       &sB[buf][rl * 64]);
            }
        };
        stage(0, 0);
        __syncthreads();
        int buf = 0;
        for (int it = 0; it < NIT; it++) {
            if (it + 1 < NIT) stage(buf ^ 1, it + 1);
#pragma unroll
            for (int k32 = 0; k32 < 64; k32 += 32) {
                bf16x8 a[4];
#pragma unroll
                for (int mi = 0; mi < 4; mi++)
                    a[mi] = *(const bf16x8*)&sA[buf][(mi * 16 + r16) * 64 + k32 + quad * 8];
                bf16x8 bf = *(const bf16x8*)&sB[buf][(w * 16 + r16) * 64 + k32 + quad * 8];
#pragma unroll
                for (int mi = 0; mi < 4; mi++)
                    acc[mi] = mfma16(a[mi], bf, acc[mi]);
            }
            __syncthreads();
            buf ^= 1;
        }
        int n = n0 + w * 16 + r16;
#pragma unroll
        for (int mi = 0; mi < 4; mi++)
#pragma unroll
            for (int r = 0; r < 4; r++) {
                int m = m0 + mi * 16 + quad * 4 + r;
                qout[(size_t)m * 1024 + n] = acc[mi][r];
            }
    }
}

// ======== attention + max-pool + logits + NLL (16 waves, L split 4-way) ======
__global__ __launch_bounds__(1024, 2) void kattn(
    int t,
    const float* __restrict__ q,             // [256][1024]
    const __hip_bfloat16* __restrict__ ctx,  // [64][256][4][1024]
    const __hip_bfloat16* __restrict__ hcur, // [256][1024]
    const __hip_bfloat16* __restrict__ WcT,  // [64][2048]
    const float* __restrict__ bcomp,         // [64]
    const int* __restrict__ actions,         // [256][32]
    float* __restrict__ nll)                 // [256]
{
    __shared__ float scacc[16][1024];        // [n*4+lq][e] raw weighted sums
    __shared__ float sM[4][4], sS[4][4];
    __shared__ float spool[1024];
    __shared__ float shb[1024];
    __shared__ float slg[64];

    int b = blockIdx.x;
    int tid = threadIdx.x;
    int lane = tid & 63, wid = tid >> 6;
    int n = wid & 3, lq = wid >> 2;          // wave handles io n, l chunk lq

    float qr[16];
    {
        const f32x4* qp = (const f32x4*)(q + (size_t)b * 1024 + lane * 16);
#pragma unroll
        for (int i = 0; i < 4; i++) { f32x4 v = qp[i];
#pragma unroll
            for (int j = 0; j < 4; j++) qr[i * 4 + j] = v[j]; }
    }

    float mx = -1e30f, ssum = 0.f;
    float cacc[16];
#pragma unroll
    for (int i = 0; i < 16; i++) cacc[i] = 0.f;

    const size_t LSTR = 1024 * 1024;         // ctx l-stride in elements
    const __hip_bfloat16* cb = ctx + ((size_t)b * 4 + n) * 1024 + lane * 16;
#pragma unroll 2
    for (int j = 0; j < 16; j++) {
        int l = lq * 16 + j;
        const bf16x8* row = (const bf16x8*)(cb + (size_t)l * LSTR);
        bf16x8 v0 = __builtin_nontemporal_load(row);
        bf16x8 v1 = __builtin_nontemporal_load(row + 1);
        float rv[16];
#pragma unroll
        for (int i = 0; i < 8; i++) { rv[i] = (float)v0[i]; rv[8 + i] = (float)v1[i]; }
        float s = 0.f;
#pragma unroll
        for (int i = 0; i < 16; i++) s += rv[i] * qr[i];
        s = wsum(s);
        float mn = fmaxf(mx, s);
        float sc = __expf(mx - mn);
        float p  = __expf(s - mn);
        ssum = ssum * sc + p;
#pragma unroll
        for (int i = 0; i < 16; i++) cacc[i] = cacc[i] * sc + p * rv[i];
        mx = mn;
    }
#pragma unroll
    for (int i = 0; i < 16; i++) scacc[wid][lane * 16 + i] = cacc[i];
    if (lane == 0) { sM[n][lq] = mx; sS[n][lq] = ssum; }
    shb[tid] = __bfloat162float(hcur[(size_t)b * 1024 + tid]);
    __syncthreads();

    // merge 4 partials per n, normalize, max-pool over n
    {
        float pool = -1e30f;
#pragma unroll
        for (int nn = 0; nn < 4; nn++) {
            float M = fmaxf(fmaxf(sM[nn][0], sM[nn][1]), fmaxf(sM[nn][2], sM[nn][3]));
            float S = 0.f, V = 0.f;
#pragma unroll
            for (int kq = 0; kq < 4; kq++) {
                float sc = __expf(sM[nn][kq] - M);
                S += sS[nn][kq] * sc;
                V += scacc[nn * 4 + kq][tid] * sc;
            }
            pool = fmaxf(pool, V / S);
        }
        spool[tid] = pool;
    }
    __syncthreads();

    // logits: wave wid computes prods wid*4 .. wid*4+3
#pragma unroll
    for (int pi = 0; pi < 4; pi++) {
        int p = wid * 4 + pi;
        const __hip_bfloat16* wr = WcT + (size_t)p * 2048;
        float s = 0.f;
#pragma unroll
        for (int jj = 0; jj < 16; jj++) {
            int e = lane + jj * 64;
            s += shb[e] * __bfloat162float(wr[e]);
            s += spool[e] * __bfloat162float(wr[1024 + e]);
        }
        s = wsum(s);
        if (lane == 0) slg[p] = s + bcomp[p];
    }
    __syncthreads();
    if (tid < 64) {
        float v = slg[tid];
        float m2 = wmaxr(v);
        float se = wsum(__expf(v - m2));
        int a = actions[b * 32 + t];
        if (tid == a) nll[b] -= (v - m2 - __logf(se));
    }
}

// ---------------- decoder init: max-pool final states over io examples -------
__global__ __launch_bounds__(256) void kinit_dec(
    const __hip_bfloat16* __restrict__ hf,  // final h (buf0): [2][1024][512]
    const float* __restrict__ cf,
    __hip_bfloat16* __restrict__ h0,        // [256][1024]
    float* __restrict__ c0)
{
    int idx = blockIdx.x * 256 + threadIdx.x;
    int b = idx >> 10, e = idx & 1023;
    int dir = e >> 9, u = e & 511;
    const __hip_bfloat16* hs = hf + (size_t)dir * 1024 * 512;
    const float* cs = cf + (size_t)dir * 1024 * 512;
    float hv = -3.4e38f, cv = -3.4e38f;
#pragma unroll
    for (int n = 0; n < 4; n++) {
        size_t ix = (size_t)(b * 4 + n) * 512 + u;
        hv = fmaxf(hv, __bfloat162float(hs[ix]));
        cv = fmaxf(cv, cs[ix]);
    }
    h0[idx] = __float2bfloat16(hv);
    c0[idx] = cv;
}

__global__ void kfinal(const float* __restrict__ nll, void* __restrict__ out,
                       const int* __restrict__ mode) {
    int i = threadIdx.x;
    if (*mode) ((__hip_bfloat16*)out)[i] = __float2bfloat16(nll[i]);
    else       ((float*)out)[i] = nll[i];
}

// -----------------------------------------------------------------------------
extern "C" void kernel_launch(void* const* d_in, const int* in_sizes, int n_in,
                              void* d_out, int out_size, void* d_ws, size_t ws_size,
                              hipStream_t stream) {
    const int* exs = (const int*)d_in[0];
    const int* cls = (const int*)d_in[1];
    const void* E_raw     = d_in[2];
    const void* WiF_raw   = d_in[3];
    const void* WhF_raw   = d_in[4];
    const void* bF_raw    = d_in[5];
    const void* WiB_raw   = d_in[6];
    const void* WhB_raw   = d_in[7];
    const void* bB_raw    = d_in[8];
    const void* Wattn_raw = d_in[9];
    const void* Wcomp_raw = d_in[10];
    const void* bcomp_raw = d_in[11];
    const void* vWi_raw   = d_in[12];
    const void* vWh_raw   = d_in[13];
    const void* vb_raw    = d_in[14];
    const void* fe_raw    = d_in[15];
    const int* actions = (const int*)d_in[16];
    (void)in_sizes; (void)n_in; (void)out_size; (void)ws_size;

    char* w = (char*)d_ws;
    size_t off = 0;
    auto take = [&](size_t bytes) -> char* {
        char* p = w + off;
        off = (off + bytes + 255) & ~(size_t)255;
        return p;
    };
    __hip_bfloat16* WhT    = (__hip_bfloat16*)take(2ull * 2048 * 512 * 2);
    __hip_bfloat16* WiT    = (__hip_bfloat16*)take(2ull * 2048 * 256 * 2);
    __hip_bfloat16* vWhT   = (__hip_bfloat16*)take(4096ull * 1024 * 2);
    __hip_bfloat16* vWiT   = (__hip_bfloat16*)take(4096ull * 1024 * 2);
    __hip_bfloat16* WattnT = (__hip_bfloat16*)take(1024ull * 1024 * 2);
    __hip_bfloat16* WcT    = (__hip_bfloat16*)take(64ull * 2048 * 2);
    __hip_bfloat16* Ebf    = (__hip_bfloat16*)take(128ull * 128 * 2);
    __hip_bfloat16* febf   = (__hip_bfloat16*)take(32ull * 1024 * 2);
    float* bFf   = (float*)take(2048 * 4);
    float* bBf   = (float*)take(2048 * 4);
    float* bcf   = (float*)take(64 * 4);
    float* vbf   = (float*)take(4096 * 4);
    float* Gtab  = (float*)take(4ull * 128 * 2048 * 4);
    float* VX    = (float*)take(32ull * 4096 * 4);
    __hip_bfloat16* hEnc = (__hip_bfloat16*)take(2ull * 2 * 1024 * 512 * 2); // [buf][dir][1024][512]
    float* cEnc = (float*)take(2ull * 1024 * 512 * 4);
    __hip_bfloat16* hDec = (__hip_bfloat16*)take(2ull * 256 * 1024 * 2);
    float* cDec = (float*)take(256ull * 1024 * 4);
    float* qbuf = (float*)take(256ull * 1024 * 4);
    float* nll  = (float*)take(256 * 4);
    int*   mode = (int*)take(256);
    __hip_bfloat16* ctx  = (__hip_bfloat16*)take(64ull * 1024 * 1024 * 2);   // [64][256][4][1024]

    hipMemsetAsync(hEnc, 0, 2ull * 1024 * 512 * 2, stream);  // h buf0, both dirs
    hipMemsetAsync(cEnc, 0, 2ull * 1024 * 512 * 4, stream);
    hipMemsetAsync(nll, 0, 256 * 4, stream);

    kdetect<<<1, 128, 0, stream>>>((const unsigned int*)E_raw, mode);

    kcvt_bf16<<<64, 256, 0, stream>>>(E_raw,  Ebf,  128 * 128, mode);
    kcvt_bf16<<<128, 256, 0, stream>>>(fe_raw, febf, 32 * 1024, mode);
    kcvt_f32<<<8, 256, 0, stream>>>(bF_raw, bFf, 2048, mode);
    kcvt_f32<<<8, 256, 0, stream>>>(bB_raw, bBf, 2048, mode);
    kcvt_f32<<<1, 256, 0, stream>>>(bcomp_raw, bcf, 64, mode);
    kcvt_f32<<<16, 256, 0, stream>>>(vb_raw, vbf, 4096, mode);

    ktranspose_cvt<<<dim3(32, 8),  256, 0, stream>>>(WhF_raw,   WhT,              512, 2048, mode);
    ktranspose_cvt<<<dim3(32, 8),  256, 0, stream>>>(WhB_raw,   WhT + 2048 * 512, 512, 2048, mode);
    ktranspose_cvt<<<dim3(32, 4),  256, 0, stream>>>(WiF_raw,   WiT,              256, 2048, mode);
    ktranspose_cvt<<<dim3(32, 4),  256, 0, stream>>>(WiB_raw,   WiT + 2048 * 256, 256, 2048, mode);
    ktranspose_cvt<<<dim3(64, 16), 256, 0, stream>>>(vWh_raw,   vWhT,            1024, 4096, mode);
    ktranspose_cvt<<<dim3(64, 16), 256, 0, stream>>>(vWi_raw,   vWiT,            1024, 4096, mode);
    ktranspose_cvt<<<dim3(16, 16), 256, 0, stream>>>(Wattn_raw, WattnT,          1024, 1024, mode);
    ktranspose_cvt<<<dim3(1, 32),  256, 0, stream>>>(Wcomp_raw, WcT,             2048, 64,   mode);

    kprep_gtab<<<256, 256, 0, stream>>>(Ebf, WiT, bFf, bBf, Gtab);
    kprep_vx<<<32, 256, 0, stream>>>(febf, vWiT, vbf, VX);

    const size_t HB = 2ull * 1024 * 512;
    for (int t = 0; t < 64; t++) {
        kenc_step<<<256, 256, 0, stream>>>(t, WhT, Gtab, exs, cls,
                                           hEnc + (size_t)(t & 1) * HB,
                                           hEnc + (size_t)((t + 1) & 1) * HB,
                                           cEnc, ctx);
    }
    kinit_dec<<<1024, 256, 0, stream>>>(hEnc, cEnc, hDec, cDec);

    const size_t HD = 256ull * 1024;
    for (int t = 0; t < 32; t++) {
        const __hip_bfloat16* hcur = hDec + (size_t)(t & 1) * HD;
        kdec_gemm<<<128, 256, 0, stream>>>(t, vWhT, WattnT, VX, hcur,
                                           hDec + (size_t)((t + 1) & 1) * HD, cDec, qbuf);
        kattn<<<256, 1024, 0, stream>>>(t, qbuf, ctx, hcur, WcT, bcf, actions, nll);
    }
    kfinal<<<1, 256, 0, stream>>>(nll, d_out, mode);
}